// Round 5
// baseline (186.254 us; speedup 1.0000x reference)
//
#include <hip/hip_runtime.h>

#define NN 2048
#define HALF 1024
#define CC 128
#define EE 65536
#define CAP 128

typedef unsigned short u16;

__device__ __forceinline__ float sigm(float v){ return 1.0f/(1.0f + __expf(-v)); }

__device__ __forceinline__ float dinv_lo(int i, const int* __restrict__ cnt,
                                         const float* __restrict__ colsum){
  return rsqrtf(1.0f + (float)cnt[i] + colsum[i]);
}
__device__ __forceinline__ float dinv_any(int i, const int* __restrict__ cnt,
                                          const float* __restrict__ colsum){
  float cs = (i < HALF) ? colsum[i] : 0.0f;
  return rsqrtf(1.0f + (float)cnt[i] + cs);
}

// ---------------- K1: prep (384 blocks) — NO matmul here anymore (Â·x commutes with W1)
//  [0,128):   SpRaw = sigmoid(my[:1024,:1024]) (8 rows/block) + colsum atomics
//  [128,384): bias-seed out (1 float4/thread) + bucket sparse edges (256 edges/block)
__global__ __launch_bounds__(256) void k_prep(
    const float* __restrict__ my, const int* __restrict__ ei,
    const float* __restrict__ bmu, const float* __restrict__ bls,
    float* __restrict__ SpRaw, float* __restrict__ colsum,
    int* __restrict__ cnt, u16* __restrict__ bucket,
    float* __restrict__ out)
{
  int b = blockIdx.x, t = threadIdx.x;
  if (b < 128) {
    int c0 = t*4;
    float cs0=0.f, cs1=0.f, cs2=0.f, cs3=0.f;
    #pragma unroll 2
    for (int rr=0; rr<8; ++rr){
      int r = b*8 + rr;
      float4 v = *(const float4*)(my + (size_t)r*NN + c0);
      float s0=sigm(v.x), s1=sigm(v.y), s2=sigm(v.z), s3=sigm(v.w);
      *(float4*)(SpRaw + (size_t)r*HALF + c0) = make_float4(s0,s1,s2,s3);
      cs0+=s0; cs1+=s1; cs2+=s2; cs3+=s3;
    }
    atomicAdd(&colsum[c0+0], cs0);
    atomicAdd(&colsum[c0+1], cs1);
    atomicAdd(&colsum[c0+2], cs2);
    atomicAdd(&colsum[c0+3], cs3);
  } else {
    int bb = b - 128;                      // [0,256)
    int gid = bb*256 + t;                  // [0,65536) float4 = full out
    int g4 = (gid & 15)*4;
    const float* bbias = (gid < 32768) ? bmu : bls;
    ((float4*)out)[gid] = make_float4(bbias[g4], bbias[g4+1], bbias[g4+2], bbias[g4+3]);
    int e = bb*256 + t;
    int s = ei[e], d = ei[EE + e];
    int slot = atomicAdd(&cnt[d], 1);
    if (slot < CAP) bucket[d*CAP + slot] = (u16)s;
  }
}

// ---------------- K2: AX = Â x  (512 blocks, NO atomics)
//  dense [0,256): 32 d × 128 f per block (4f×4d per lane), 8 r-chunks of 128 -> DP[chunk]
//  sparse [256,512): 8 dst/block, half-wave float4 -> SP
__global__ __launch_bounds__(256) void k_agg1(
  const float* __restrict__ SpRaw, const float* __restrict__ x,
  const int* __restrict__ cnt, const float* __restrict__ colsum,
  const u16* __restrict__ bucket,
  float* __restrict__ SP, float* __restrict__ DP)
{
  int b = blockIdx.x, t = threadIdx.x;
  if (b < 256) {
    __shared__ float srow[128];
    int chunk = b & 7, r0 = chunk*128;
    if (t < 128) srow[t] = dinv_lo(r0 + t, cnt, colsum);
    __syncthreads();
    int sub = t >> 5, l = t & 31;
    int f0 = l*4;
    int dbase = (b>>3)*32 + sub*4;
    float4 a0 = make_float4(0.f,0.f,0.f,0.f), a1 = a0, a2 = a0, a3 = a0;
    #pragma unroll 2
    for (int rr=0; rr<128; ++rr){
      int r = r0 + rr;
      float4 xv = *(const float4*)(x + (size_t)r*CC + f0);
      float sc = srow[rr];
      float x0=xv.x*sc, x1=xv.y*sc, x2=xv.z*sc, x3=xv.w*sc;
      float4 s4 = *(const float4*)(SpRaw + (size_t)r*HALF + dbase);
      a0.x=fmaf(s4.x,x0,a0.x); a0.y=fmaf(s4.x,x1,a0.y); a0.z=fmaf(s4.x,x2,a0.z); a0.w=fmaf(s4.x,x3,a0.w);
      a1.x=fmaf(s4.y,x0,a1.x); a1.y=fmaf(s4.y,x1,a1.y); a1.z=fmaf(s4.y,x2,a1.z); a1.w=fmaf(s4.y,x3,a1.w);
      a2.x=fmaf(s4.z,x0,a2.x); a2.y=fmaf(s4.z,x1,a2.y); a2.z=fmaf(s4.z,x2,a2.z); a2.w=fmaf(s4.z,x3,a2.w);
      a3.x=fmaf(s4.w,x0,a3.x); a3.y=fmaf(s4.w,x1,a3.y); a3.z=fmaf(s4.w,x2,a3.z); a3.w=fmaf(s4.w,x3,a3.w);
    }
    float d0=dinv_lo(dbase+0,cnt,colsum), d1=dinv_lo(dbase+1,cnt,colsum);
    float d2=dinv_lo(dbase+2,cnt,colsum), d3=dinv_lo(dbase+3,cnt,colsum);
    float* o = DP + ((size_t)chunk*HALF + dbase)*CC + f0;
    *(float4*)(o + 0*CC) = make_float4(a0.x*d0, a0.y*d0, a0.z*d0, a0.w*d0);
    *(float4*)(o + 1*CC) = make_float4(a1.x*d1, a1.y*d1, a1.z*d1, a1.w*d1);
    *(float4*)(o + 2*CC) = make_float4(a2.x*d2, a2.y*d2, a2.z*d2, a2.w*d2);
    *(float4*)(o + 3*CC) = make_float4(a3.x*d3, a3.y*d3, a3.z*d3, a3.w*d3);
  } else {
    __shared__ float sdinv[NN];
    #pragma unroll
    for (int i=0;i<8;i++){
      int j = i*256 + t;
      float cs = (j < HALF) ? colsum[j] : 0.0f;
      sdinv[j] = rsqrtf(1.0f + (float)cnt[j] + cs);
    }
    __syncthreads();
    int w = t>>6, hw = (t>>5)&1, l = t&31;
    int d = (b-256)*8 + w*2 + hw;
    int f0 = l*4;
    float dd = sdinv[d];
    float4 sv = *(const float4*)(x + (size_t)d*CC + f0);
    float ax=dd*sv.x, ay=dd*sv.y, az=dd*sv.z, aw=dd*sv.w;   // self-loop
    int m = cnt[d]; m = m > CAP ? CAP : m;
    const u16* bk = bucket + d*CAP;
    int j = 0;
    for (; j+1 < m; j += 2){
      unsigned pr = *(const unsigned*)(bk + j);
      int s0 = pr & 0xffff, s1 = pr >> 16;
      float w0 = sdinv[s0], w1 = sdinv[s1];
      float4 v0 = *(const float4*)(x + (size_t)s0*CC + f0);
      float4 v1 = *(const float4*)(x + (size_t)s1*CC + f0);
      ax=fmaf(w0,v0.x,ax); ay=fmaf(w0,v0.y,ay); az=fmaf(w0,v0.z,az); aw=fmaf(w0,v0.w,aw);
      ax=fmaf(w1,v1.x,ax); ay=fmaf(w1,v1.y,ay); az=fmaf(w1,v1.z,az); aw=fmaf(w1,v1.w,aw);
    }
    if (j < m){
      int s0 = bk[j];
      float w0 = sdinv[s0];
      float4 v0 = *(const float4*)(x + (size_t)s0*CC + f0);
      ax=fmaf(w0,v0.x,ax); ay=fmaf(w0,v0.y,ay); az=fmaf(w0,v0.z,az); aw=fmaf(w0,v0.w,aw);
    }
    *(float4*)(SP + (size_t)d*CC + f0) = make_float4(dd*ax, dd*ay, dd*az, dd*aw);
  }
}

// ---------------- K3: mid (512 blocks, 4 rows each), DOUBLE matmul:
//  AX = SP + sum_8 DP;  hid = relu(AX @ W1 + b1);  Gm = (hid @ [Wmu|Wls]) * dinv[row]
__global__ __launch_bounds__(256) void k_mid(
  const float* __restrict__ SP, const float* __restrict__ DP,
  const float* __restrict__ b1, const float* __restrict__ W1,
  const float* __restrict__ Wmu, const float* __restrict__ Wls,
  const int* __restrict__ cnt, const float* __restrict__ colsum,
  float* __restrict__ Gm)
{
  __shared__ float la[4][CC];
  __shared__ float lb[4][CC];
  int b = blockIdx.x, t = threadIdx.x;
  int row0 = b*4;
  #pragma unroll
  for (int i=0;i<2;i++){
    int idx = i*256 + t;                  // 0..511 covers 4 rows x 128
    int r = row0 + (idx>>7), c = idx & 127;
    float v = SP[(size_t)r*CC + c];
    if (r < HALF){
      #pragma unroll
      for (int k=0;k<8;k++) v += DP[((size_t)k*HALF + r)*CC + c];
    }
    la[idx>>7][c] = v;
  }
  __syncthreads();
  int f = t & 127, rh = t >> 7;
  {
    const float4* a0 = (const float4*)la[rh*2+0];
    const float4* a1 = (const float4*)la[rh*2+1];
    float o0=0.f, o1=0.f;
    #pragma unroll 4
    for (int k4=0;k4<32;k4++){
      float4 v0=a0[k4], v1=a1[k4];
      float w0 = W1[(k4*4+0)*CC + f];
      float w1 = W1[(k4*4+1)*CC + f];
      float w2 = W1[(k4*4+2)*CC + f];
      float w3 = W1[(k4*4+3)*CC + f];
      o0=fmaf(v0.x,w0,o0); o0=fmaf(v0.y,w1,o0); o0=fmaf(v0.z,w2,o0); o0=fmaf(v0.w,w3,o0);
      o1=fmaf(v1.x,w0,o1); o1=fmaf(v1.y,w1,o1); o1=fmaf(v1.z,w2,o1); o1=fmaf(v1.w,w3,o1);
    }
    float bb = b1[f];
    o0 += bb; o1 += bb;
    lb[rh*2+0][f] = o0 > 0.f ? o0 : 0.f;
    lb[rh*2+1][f] = o1 > 0.f ? o1 : 0.f;
  }
  __syncthreads();
  {
    int g = f & 63;
    const float* W = (f < 64) ? Wmu : Wls;
    const float4* a0 = (const float4*)lb[rh*2+0];
    const float4* a1 = (const float4*)lb[rh*2+1];
    float o0=0.f, o1=0.f;
    #pragma unroll 4
    for (int k4=0;k4<32;k4++){
      float4 v0=a0[k4], v1=a1[k4];
      float w0 = W[(k4*4+0)*64 + g];
      float w1 = W[(k4*4+1)*64 + g];
      float w2 = W[(k4*4+2)*64 + g];
      float w3 = W[(k4*4+3)*64 + g];
      o0=fmaf(v0.x,w0,o0); o0=fmaf(v0.y,w1,o0); o0=fmaf(v0.z,w2,o0); o0=fmaf(v0.w,w3,o0);
      o1=fmaf(v1.x,w0,o1); o1=fmaf(v1.y,w1,o1); o1=fmaf(v1.z,w2,o1); o1=fmaf(v1.w,w3,o1);
    }
    int rA = row0 + rh*2;
    Gm[(size_t)(rA+0)*CC + f] = o0 * dinv_any(rA+0, cnt, colsum);
    Gm[(size_t)(rA+1)*CC + f] = o1 * dinv_any(rA+1, cnt, colsum);
  }
}

// ---------------- K4: out += Â-apply(Gm)  (384 blocks, atomics into bias-seeded out)
//  dense [0,128): 32 d × 128 f per block (4f×4d per lane), 4 r-chunks of 256
//  sparse [128,384): 8 dst/block, half-wave float4
__global__ __launch_bounds__(256) void k_agg2(
  const float* __restrict__ SpRaw, const float* __restrict__ Gm,
  const int* __restrict__ cnt, const float* __restrict__ colsum,
  const u16* __restrict__ bucket, float* __restrict__ out)
{
  int b = blockIdx.x, t = threadIdx.x;
  if (b < 128) {
    int sub = t >> 5, l = t & 31;
    int f0 = l*4;
    int dbase = (b>>2)*32 + sub*4;
    int r0 = (b&3)*256;
    float4 a0 = make_float4(0.f,0.f,0.f,0.f), a1 = a0, a2 = a0, a3 = a0;
    #pragma unroll 2
    for (int rr=0; rr<256; ++rr){
      int r = r0 + rr;
      float4 gv = *(const float4*)(Gm + (size_t)r*CC + f0);   // pre-scaled by dinv[r]
      float4 s4 = *(const float4*)(SpRaw + (size_t)r*HALF + dbase);
      a0.x=fmaf(s4.x,gv.x,a0.x); a0.y=fmaf(s4.x,gv.y,a0.y); a0.z=fmaf(s4.x,gv.z,a0.z); a0.w=fmaf(s4.x,gv.w,a0.w);
      a1.x=fmaf(s4.y,gv.x,a1.x); a1.y=fmaf(s4.y,gv.y,a1.y); a1.z=fmaf(s4.y,gv.z,a1.z); a1.w=fmaf(s4.y,gv.w,a1.w);
      a2.x=fmaf(s4.z,gv.x,a2.x); a2.y=fmaf(s4.z,gv.y,a2.y); a2.z=fmaf(s4.z,gv.z,a2.z); a2.w=fmaf(s4.z,gv.w,a2.w);
      a3.x=fmaf(s4.w,gv.x,a3.x); a3.y=fmaf(s4.w,gv.y,a3.y); a3.z=fmaf(s4.w,gv.z,a3.z); a3.w=fmaf(s4.w,gv.w,a3.w);
    }
    size_t obase = (f0 < 64) ? 0 : (size_t)NN*64;
    int g0 = f0 & 63;
    float d0=dinv_lo(dbase+0,cnt,colsum), d1=dinv_lo(dbase+1,cnt,colsum);
    float d2=dinv_lo(dbase+2,cnt,colsum), d3=dinv_lo(dbase+3,cnt,colsum);
    float* o = out + obase + (size_t)dbase*64 + g0;
    atomicAdd(o + 0*64 + 0, a0.x*d0); atomicAdd(o + 0*64 + 1, a0.y*d0);
    atomicAdd(o + 0*64 + 2, a0.z*d0); atomicAdd(o + 0*64 + 3, a0.w*d0);
    atomicAdd(o + 1*64 + 0, a1.x*d1); atomicAdd(o + 1*64 + 1, a1.y*d1);
    atomicAdd(o + 1*64 + 2, a1.z*d1); atomicAdd(o + 1*64 + 3, a1.w*d1);
    atomicAdd(o + 2*64 + 0, a2.x*d2); atomicAdd(o + 2*64 + 1, a2.y*d2);
    atomicAdd(o + 2*64 + 2, a2.z*d2); atomicAdd(o + 2*64 + 3, a2.w*d2);
    atomicAdd(o + 3*64 + 0, a3.x*d3); atomicAdd(o + 3*64 + 1, a3.y*d3);
    atomicAdd(o + 3*64 + 2, a3.z*d3); atomicAdd(o + 3*64 + 3, a3.w*d3);
  } else {
    int w = t>>6, hw = (t>>5)&1, l = t&31;
    int d = (b-128)*8 + w*2 + hw;
    int f0 = l*4;
    size_t obase = (f0 < 64) ? 0 : (size_t)NN*64;
    int g0 = f0 & 63;
    float4 a = *(const float4*)(Gm + (size_t)d*CC + f0);      // self (pre-scaled)
    float ax=a.x, ay=a.y, az=a.z, aw=a.w;
    int m = cnt[d]; m = m > CAP ? CAP : m;
    const u16* bk = bucket + d*CAP;
    int j = 0;
    for (; j+1 < m; j += 2){
      unsigned pr = *(const unsigned*)(bk + j);
      int s0 = pr & 0xffff, s1 = pr >> 16;
      float4 v0 = *(const float4*)(Gm + (size_t)s0*CC + f0);
      float4 v1 = *(const float4*)(Gm + (size_t)s1*CC + f0);
      ax += v0.x + v1.x; ay += v0.y + v1.y;
      az += v0.z + v1.z; aw += v0.w + v1.w;
    }
    if (j < m){
      int s0 = bk[j];
      float4 v0 = *(const float4*)(Gm + (size_t)s0*CC + f0);
      ax += v0.x; ay += v0.y; az += v0.z; aw += v0.w;
    }
    float dd = dinv_any(d, cnt, colsum);
    float* o = out + obase + (size_t)d*64 + g0;
    atomicAdd(o + 0, dd*ax); atomicAdd(o + 1, dd*ay);
    atomicAdd(o + 2, dd*az); atomicAdd(o + 3, dd*aw);
  }
}

extern "C" void kernel_launch(void* const* d_in, const int* in_sizes, int n_in,
                              void* d_out, int out_size, void* d_ws, size_t ws_size,
                              hipStream_t stream)
{
  (void)in_sizes; (void)n_in; (void)out_size; (void)ws_size;
  const float* x   = (const float*)d_in[0];
  const float* my  = (const float*)d_in[1];
  const float* W1  = (const float*)d_in[2];
  const float* b1  = (const float*)d_in[3];
  const float* Wmu = (const float*)d_in[4];
  const float* bmu = (const float*)d_in[5];
  const float* Wls = (const float*)d_in[6];
  const float* bls = (const float*)d_in[7];
  const int*   ei  = (const int*)d_in[8];
  float* out = (float*)d_out;
  char* ws = (char*)d_ws;

  // ws layout — memset covers [0, 12288): cnt, colsum
  int*   cnt    = (int*)  (ws + 0);        //    8192 B (memset 0)
  float* colsum = (float*)(ws + 8192);     //    4096 B (memset 0)
  u16*   bucket = (u16*)  (ws + 12288);    //  524288 B
  float* SpRaw  = (float*)(ws + 536576);   // 4194304 B
  float* Gm     = (float*)(ws + 4730880);  // 1048576 B
  float* SP     = (float*)(ws + 5779456);  // 1048576 B
  float* DP     = (float*)(ws + 6828032);  // 4194304 B  (8*1024*128*4)

  hipMemsetAsync(ws, 0, 12288, stream);
  k_prep<<<384, 256, 0, stream>>>(my, ei, bmu, bls, SpRaw, colsum, cnt, bucket, out);
  k_agg1<<<512, 256, 0, stream>>>(SpRaw, x, cnt, colsum, bucket, SP, DP);
  k_mid <<<512, 256, 0, stream>>>(SP, DP, b1, W1, Wmu, Wls, cnt, colsum, Gm);
  k_agg2<<<384, 256, 0, stream>>>(SpRaw, Gm, cnt, colsum, bucket, out);
}

// Round 6
// 160.446 us; speedup vs baseline: 1.1609x; 1.1609x over previous
//
#include <hip/hip_runtime.h>

#define NN 2048
#define HALF 1024
#define CC 128
#define EE 65536
#define CAP 128

typedef unsigned short u16;

__device__ __forceinline__ float sigm(float v){ return 1.0f/(1.0f + __expf(-v)); }

__device__ __forceinline__ float dinv_lo(int i, const int* __restrict__ cnt,
                                         const float* __restrict__ colsum){
  return rsqrtf(1.0f + (float)cnt[i] + colsum[i]);
}
__device__ __forceinline__ float dinv_any(int i, const int* __restrict__ cnt,
                                          const float* __restrict__ colsum){
  float cs = (i < HALF) ? colsum[i] : 0.0f;
  return rsqrtf(1.0f + (float)cnt[i] + cs);
}

// ---------------- K1: prep (384 blocks) — no matmul (Â·x commutes with W1)
//  [0,128):   SpRaw = sigmoid(my[:1024,:1024]) (8 rows/block) + colsum atomics
//  [128,384): bias-seed out (1 float4/thread) + bucket sparse edges (256 edges/block)
__global__ __launch_bounds__(256) void k_prep(
    const float* __restrict__ my, const int* __restrict__ ei,
    const float* __restrict__ bmu, const float* __restrict__ bls,
    float* __restrict__ SpRaw, float* __restrict__ colsum,
    int* __restrict__ cnt, u16* __restrict__ bucket,
    float* __restrict__ out)
{
  int b = blockIdx.x, t = threadIdx.x;
  if (b < 128) {
    int c0 = t*4;
    float cs0=0.f, cs1=0.f, cs2=0.f, cs3=0.f;
    #pragma unroll 2
    for (int rr=0; rr<8; ++rr){
      int r = b*8 + rr;
      float4 v = *(const float4*)(my + (size_t)r*NN + c0);
      float s0=sigm(v.x), s1=sigm(v.y), s2=sigm(v.z), s3=sigm(v.w);
      *(float4*)(SpRaw + (size_t)r*HALF + c0) = make_float4(s0,s1,s2,s3);
      cs0+=s0; cs1+=s1; cs2+=s2; cs3+=s3;
    }
    atomicAdd(&colsum[c0+0], cs0);
    atomicAdd(&colsum[c0+1], cs1);
    atomicAdd(&colsum[c0+2], cs2);
    atomicAdd(&colsum[c0+3], cs3);
  } else {
    int bb = b - 128;                      // [0,256)
    int gid = bb*256 + t;                  // [0,65536) float4 = full out
    int g4 = (gid & 15)*4;
    const float* bbias = (gid < 32768) ? bmu : bls;
    ((float4*)out)[gid] = make_float4(bbias[g4], bbias[g4+1], bbias[g4+2], bbias[g4+3]);
    int e = bb*256 + t;
    int s = ei[e], d = ei[EE + e];
    int slot = atomicAdd(&cnt[d], 1);
    if (slot < CAP) bucket[d*CAP + slot] = (u16)s;
  }
}

// ---------------- K2: AX = Â x  (768 blocks, NO atomics)
//  dense [0,512): 16 d/block, float2/lane, 8 r-chunks of 128 -> DP[chunk]
//                 explicit 4-row load batching for MLP
//  sparse [512,768): 8 dst/block, half-wave float4 -> SP
__global__ __launch_bounds__(256) void k_agg1(
  const float* __restrict__ SpRaw, const float* __restrict__ x,
  const int* __restrict__ cnt, const float* __restrict__ colsum,
  const u16* __restrict__ bucket,
  float* __restrict__ SP, float* __restrict__ DP)
{
  int b = blockIdx.x, t = threadIdx.x;
  if (b < 512) {
    __shared__ float srow[128];
    int chunk = b & 7, r0 = chunk*128;
    if (t < 128) srow[t] = dinv_lo(r0 + t, cnt, colsum);
    __syncthreads();
    int lane = t & 63, f0 = lane*2;
    int dbase = (b>>3)*16 + (t>>6)*4;
    float a00=0.f,a01=0.f,a10=0.f,a11=0.f,a20=0.f,a21=0.f,a30=0.f,a31=0.f;
    #pragma unroll 2
    for (int rr=0; rr<128; rr+=4){
      int r = r0 + rr;
      // batch 8 independent loads first (MLP)
      float2 v0 = *(const float2*)(x + (size_t)(r+0)*CC + f0);
      float2 v1 = *(const float2*)(x + (size_t)(r+1)*CC + f0);
      float2 v2 = *(const float2*)(x + (size_t)(r+2)*CC + f0);
      float2 v3 = *(const float2*)(x + (size_t)(r+3)*CC + f0);
      float4 s0 = *(const float4*)(SpRaw + (size_t)(r+0)*HALF + dbase);
      float4 s1 = *(const float4*)(SpRaw + (size_t)(r+1)*HALF + dbase);
      float4 s2 = *(const float4*)(SpRaw + (size_t)(r+2)*HALF + dbase);
      float4 s3 = *(const float4*)(SpRaw + (size_t)(r+3)*HALF + dbase);
      float c0 = srow[rr+0], c1 = srow[rr+1], c2 = srow[rr+2], c3 = srow[rr+3];
      float fx, fy;
      fx = v0.x*c0; fy = v0.y*c0;
      a00=fmaf(s0.x,fx,a00); a01=fmaf(s0.x,fy,a01);
      a10=fmaf(s0.y,fx,a10); a11=fmaf(s0.y,fy,a11);
      a20=fmaf(s0.z,fx,a20); a21=fmaf(s0.z,fy,a21);
      a30=fmaf(s0.w,fx,a30); a31=fmaf(s0.w,fy,a31);
      fx = v1.x*c1; fy = v1.y*c1;
      a00=fmaf(s1.x,fx,a00); a01=fmaf(s1.x,fy,a01);
      a10=fmaf(s1.y,fx,a10); a11=fmaf(s1.y,fy,a11);
      a20=fmaf(s1.z,fx,a20); a21=fmaf(s1.z,fy,a21);
      a30=fmaf(s1.w,fx,a30); a31=fmaf(s1.w,fy,a31);
      fx = v2.x*c2; fy = v2.y*c2;
      a00=fmaf(s2.x,fx,a00); a01=fmaf(s2.x,fy,a01);
      a10=fmaf(s2.y,fx,a10); a11=fmaf(s2.y,fy,a11);
      a20=fmaf(s2.z,fx,a20); a21=fmaf(s2.z,fy,a21);
      a30=fmaf(s2.w,fx,a30); a31=fmaf(s2.w,fy,a31);
      fx = v3.x*c3; fy = v3.y*c3;
      a00=fmaf(s3.x,fx,a00); a01=fmaf(s3.x,fy,a01);
      a10=fmaf(s3.y,fx,a10); a11=fmaf(s3.y,fy,a11);
      a20=fmaf(s3.z,fx,a20); a21=fmaf(s3.z,fy,a21);
      a30=fmaf(s3.w,fx,a30); a31=fmaf(s3.w,fy,a31);
    }
    float d0=dinv_lo(dbase+0,cnt,colsum), d1=dinv_lo(dbase+1,cnt,colsum);
    float d2=dinv_lo(dbase+2,cnt,colsum), d3=dinv_lo(dbase+3,cnt,colsum);
    float* o = DP + ((size_t)chunk*HALF + dbase)*CC + f0;
    o[0*CC+0]=a00*d0; o[0*CC+1]=a01*d0;
    o[1*CC+0]=a10*d1; o[1*CC+1]=a11*d1;
    o[2*CC+0]=a20*d2; o[2*CC+1]=a21*d2;
    o[3*CC+0]=a30*d3; o[3*CC+1]=a31*d3;
  } else {
    __shared__ float sdinv[NN];
    #pragma unroll
    for (int i=0;i<8;i++){
      int j = i*256 + t;
      float cs = (j < HALF) ? colsum[j] : 0.0f;
      sdinv[j] = rsqrtf(1.0f + (float)cnt[j] + cs);
    }
    __syncthreads();
    int w = t>>6, hw = (t>>5)&1, l = t&31;
    int d = (b-512)*8 + w*2 + hw;
    int f0 = l*4;
    float dd = sdinv[d];
    float4 sv = *(const float4*)(x + (size_t)d*CC + f0);
    float ax=dd*sv.x, ay=dd*sv.y, az=dd*sv.z, aw=dd*sv.w;   // self-loop
    int m = cnt[d]; m = m > CAP ? CAP : m;
    const u16* bk = bucket + d*CAP;
    int j = 0;
    for (; j+1 < m; j += 2){
      unsigned pr = *(const unsigned*)(bk + j);
      int s0 = pr & 0xffff, s1 = pr >> 16;
      float w0 = sdinv[s0], w1 = sdinv[s1];
      float4 v0 = *(const float4*)(x + (size_t)s0*CC + f0);
      float4 v1 = *(const float4*)(x + (size_t)s1*CC + f0);
      ax=fmaf(w0,v0.x,ax); ay=fmaf(w0,v0.y,ay); az=fmaf(w0,v0.z,az); aw=fmaf(w0,v0.w,aw);
      ax=fmaf(w1,v1.x,ax); ay=fmaf(w1,v1.y,ay); az=fmaf(w1,v1.z,az); aw=fmaf(w1,v1.w,aw);
    }
    if (j < m){
      int s0 = bk[j];
      float w0 = sdinv[s0];
      float4 v0 = *(const float4*)(x + (size_t)s0*CC + f0);
      ax=fmaf(w0,v0.x,ax); ay=fmaf(w0,v0.y,ay); az=fmaf(w0,v0.z,az); aw=fmaf(w0,v0.w,aw);
    }
    *(float4*)(SP + (size_t)d*CC + f0) = make_float4(dd*ax, dd*ay, dd*az, dd*aw);
  }
}

// ---------------- K3: mid (512 blocks, 4 rows each), DOUBLE matmul:
//  AX = SP + sum_8 DP;  hid = relu(AX @ W1 + b1);  Gm = (hid @ [Wmu|Wls]) * dinv[row]
__global__ __launch_bounds__(256) void k_mid(
  const float* __restrict__ SP, const float* __restrict__ DP,
  const float* __restrict__ b1, const float* __restrict__ W1,
  const float* __restrict__ Wmu, const float* __restrict__ Wls,
  const int* __restrict__ cnt, const float* __restrict__ colsum,
  float* __restrict__ Gm)
{
  __shared__ float la[4][CC];
  __shared__ float lb[4][CC];
  int b = blockIdx.x, t = threadIdx.x;
  int row0 = b*4;
  #pragma unroll
  for (int i=0;i<2;i++){
    int idx = i*256 + t;                  // 0..511 covers 4 rows x 128
    int r = row0 + (idx>>7), c = idx & 127;
    float v = SP[(size_t)r*CC + c];
    if (r < HALF){
      #pragma unroll
      for (int k=0;k<8;k++) v += DP[((size_t)k*HALF + r)*CC + c];
    }
    la[idx>>7][c] = v;
  }
  __syncthreads();
  int f = t & 127, rh = t >> 7;
  {
    const float4* a0 = (const float4*)la[rh*2+0];
    const float4* a1 = (const float4*)la[rh*2+1];
    float o0=0.f, o1=0.f;
    #pragma unroll 4
    for (int k4=0;k4<32;k4++){
      float4 v0=a0[k4], v1=a1[k4];
      float w0 = W1[(k4*4+0)*CC + f];
      float w1 = W1[(k4*4+1)*CC + f];
      float w2 = W1[(k4*4+2)*CC + f];
      float w3 = W1[(k4*4+3)*CC + f];
      o0=fmaf(v0.x,w0,o0); o0=fmaf(v0.y,w1,o0); o0=fmaf(v0.z,w2,o0); o0=fmaf(v0.w,w3,o0);
      o1=fmaf(v1.x,w0,o1); o1=fmaf(v1.y,w1,o1); o1=fmaf(v1.z,w2,o1); o1=fmaf(v1.w,w3,o1);
    }
    float bb = b1[f];
    o0 += bb; o1 += bb;
    lb[rh*2+0][f] = o0 > 0.f ? o0 : 0.f;
    lb[rh*2+1][f] = o1 > 0.f ? o1 : 0.f;
  }
  __syncthreads();
  {
    int g = f & 63;
    const float* W = (f < 64) ? Wmu : Wls;
    const float4* a0 = (const float4*)lb[rh*2+0];
    const float4* a1 = (const float4*)lb[rh*2+1];
    float o0=0.f, o1=0.f;
    #pragma unroll 4
    for (int k4=0;k4<32;k4++){
      float4 v0=a0[k4], v1=a1[k4];
      float w0 = W[(k4*4+0)*64 + g];
      float w1 = W[(k4*4+1)*64 + g];
      float w2 = W[(k4*4+2)*64 + g];
      float w3 = W[(k4*4+3)*64 + g];
      o0=fmaf(v0.x,w0,o0); o0=fmaf(v0.y,w1,o0); o0=fmaf(v0.z,w2,o0); o0=fmaf(v0.w,w3,o0);
      o1=fmaf(v1.x,w0,o1); o1=fmaf(v1.y,w1,o1); o1=fmaf(v1.z,w2,o1); o1=fmaf(v1.w,w3,o1);
    }
    int rA = row0 + rh*2;
    Gm[(size_t)(rA+0)*CC + f] = o0 * dinv_any(rA+0, cnt, colsum);
    Gm[(size_t)(rA+1)*CC + f] = o1 * dinv_any(rA+1, cnt, colsum);
  }
}

// ---------------- K4: out += Â-apply(Gm)  (768 blocks, atomics into bias-seeded out)
//  dense [0,512): 16 d/block, float2/lane, 8 r-chunks of 128, 4-row load batching
//  sparse [512,768): 8 dst/block, half-wave float4
__global__ __launch_bounds__(256) void k_agg2(
  const float* __restrict__ SpRaw, const float* __restrict__ Gm,
  const int* __restrict__ cnt, const float* __restrict__ colsum,
  const u16* __restrict__ bucket, float* __restrict__ out)
{
  int b = blockIdx.x, t = threadIdx.x;
  if (b < 512) {
    int lane = t & 63, f0 = lane*2;
    size_t obase = (f0 < 64) ? 0 : (size_t)NN*64;
    int g0 = f0 & 63;
    int dbase = (b>>3)*16 + (t>>6)*4;
    int r0 = (b&7)*128;
    float a00=0.f,a01=0.f,a10=0.f,a11=0.f,a20=0.f,a21=0.f,a30=0.f,a31=0.f;
    #pragma unroll 2
    for (int rr=0; rr<128; rr+=4){
      int r = r0 + rr;
      float2 v0 = *(const float2*)(Gm + (size_t)(r+0)*CC + f0);   // pre-scaled by dinv[r]
      float2 v1 = *(const float2*)(Gm + (size_t)(r+1)*CC + f0);
      float2 v2 = *(const float2*)(Gm + (size_t)(r+2)*CC + f0);
      float2 v3 = *(const float2*)(Gm + (size_t)(r+3)*CC + f0);
      float4 s0 = *(const float4*)(SpRaw + (size_t)(r+0)*HALF + dbase);
      float4 s1 = *(const float4*)(SpRaw + (size_t)(r+1)*HALF + dbase);
      float4 s2 = *(const float4*)(SpRaw + (size_t)(r+2)*HALF + dbase);
      float4 s3 = *(const float4*)(SpRaw + (size_t)(r+3)*HALF + dbase);
      a00=fmaf(s0.x,v0.x,a00); a01=fmaf(s0.x,v0.y,a01);
      a10=fmaf(s0.y,v0.x,a10); a11=fmaf(s0.y,v0.y,a11);
      a20=fmaf(s0.z,v0.x,a20); a21=fmaf(s0.z,v0.y,a21);
      a30=fmaf(s0.w,v0.x,a30); a31=fmaf(s0.w,v0.y,a31);
      a00=fmaf(s1.x,v1.x,a00); a01=fmaf(s1.x,v1.y,a01);
      a10=fmaf(s1.y,v1.x,a10); a11=fmaf(s1.y,v1.y,a11);
      a20=fmaf(s1.z,v1.x,a20); a21=fmaf(s1.z,v1.y,a21);
      a30=fmaf(s1.w,v1.x,a30); a31=fmaf(s1.w,v1.y,a31);
      a00=fmaf(s2.x,v2.x,a00); a01=fmaf(s2.x,v2.y,a01);
      a10=fmaf(s2.y,v2.x,a10); a11=fmaf(s2.y,v2.y,a11);
      a20=fmaf(s2.z,v2.x,a20); a21=fmaf(s2.z,v2.y,a21);
      a30=fmaf(s2.w,v2.x,a30); a31=fmaf(s2.w,v2.y,a31);
      a00=fmaf(s3.x,v3.x,a00); a01=fmaf(s3.x,v3.y,a01);
      a10=fmaf(s3.y,v3.x,a10); a11=fmaf(s3.y,v3.y,a11);
      a20=fmaf(s3.z,v3.x,a20); a21=fmaf(s3.z,v3.y,a21);
      a30=fmaf(s3.w,v3.x,a30); a31=fmaf(s3.w,v3.y,a31);
    }
    float d0=dinv_lo(dbase+0,cnt,colsum), d1=dinv_lo(dbase+1,cnt,colsum);
    float d2=dinv_lo(dbase+2,cnt,colsum), d3=dinv_lo(dbase+3,cnt,colsum);
    float* o = out + obase + (size_t)dbase*64 + g0;
    atomicAdd(o + 0*64 + 0, a00*d0); atomicAdd(o + 0*64 + 1, a01*d0);
    atomicAdd(o + 1*64 + 0, a10*d1); atomicAdd(o + 1*64 + 1, a11*d1);
    atomicAdd(o + 2*64 + 0, a20*d2); atomicAdd(o + 2*64 + 1, a21*d2);
    atomicAdd(o + 3*64 + 0, a30*d3); atomicAdd(o + 3*64 + 1, a31*d3);
  } else {
    int w = t>>6, hw = (t>>5)&1, l = t&31;
    int d = (b-512)*8 + w*2 + hw;
    int f0 = l*4;
    size_t obase = (f0 < 64) ? 0 : (size_t)NN*64;
    int g0 = f0 & 63;
    float4 a = *(const float4*)(Gm + (size_t)d*CC + f0);      // self (pre-scaled)
    float ax=a.x, ay=a.y, az=a.z, aw=a.w;
    int m = cnt[d]; m = m > CAP ? CAP : m;
    const u16* bk = bucket + d*CAP;
    int j = 0;
    for (; j+1 < m; j += 2){
      unsigned pr = *(const unsigned*)(bk + j);
      int s0 = pr & 0xffff, s1 = pr >> 16;
      float4 v0 = *(const float4*)(Gm + (size_t)s0*CC + f0);
      float4 v1 = *(const float4*)(Gm + (size_t)s1*CC + f0);
      ax += v0.x + v1.x; ay += v0.y + v1.y;
      az += v0.z + v1.z; aw += v0.w + v1.w;
    }
    if (j < m){
      int s0 = bk[j];
      float4 v0 = *(const float4*)(Gm + (size_t)s0*CC + f0);
      ax += v0.x; ay += v0.y; az += v0.z; aw += v0.w;
    }
    float dd = dinv_any(d, cnt, colsum);
    float* o = out + obase + (size_t)d*64 + g0;
    atomicAdd(o + 0, dd*ax); atomicAdd(o + 1, dd*ay);
    atomicAdd(o + 2, dd*az); atomicAdd(o + 3, dd*aw);
  }
}

extern "C" void kernel_launch(void* const* d_in, const int* in_sizes, int n_in,
                              void* d_out, int out_size, void* d_ws, size_t ws_size,
                              hipStream_t stream)
{
  (void)in_sizes; (void)n_in; (void)out_size; (void)ws_size;
  const float* x   = (const float*)d_in[0];
  const float* my  = (const float*)d_in[1];
  const float* W1  = (const float*)d_in[2];
  const float* b1  = (const float*)d_in[3];
  const float* Wmu = (const float*)d_in[4];
  const float* bmu = (const float*)d_in[5];
  const float* Wls = (const float*)d_in[6];
  const float* bls = (const float*)d_in[7];
  const int*   ei  = (const int*)d_in[8];
  float* out = (float*)d_out;
  char* ws = (char*)d_ws;

  // ws layout — memset covers [0, 12288): cnt, colsum
  int*   cnt    = (int*)  (ws + 0);        //    8192 B (memset 0)
  float* colsum = (float*)(ws + 8192);     //    4096 B (memset 0)
  u16*   bucket = (u16*)  (ws + 12288);    //  524288 B
  float* SpRaw  = (float*)(ws + 536576);   // 4194304 B
  float* Gm     = (float*)(ws + 4730880);  // 1048576 B
  float* SP     = (float*)(ws + 5779456);  // 1048576 B
  float* DP     = (float*)(ws + 6828032);  // 4194304 B  (8*1024*128*4)

  hipMemsetAsync(ws, 0, 12288, stream);
  k_prep<<<384, 256, 0, stream>>>(my, ei, bmu, bls, SpRaw, colsum, cnt, bucket, out);
  k_agg1<<<768, 256, 0, stream>>>(SpRaw, x, cnt, colsum, bucket, SP, DP);
  k_mid <<<512, 256, 0, stream>>>(SP, DP, b1, W1, Wmu, Wls, cnt, colsum, Gm);
  k_agg2<<<768, 256, 0, stream>>>(SpRaw, Gm, cnt, colsum, bucket, out);
}

// Round 7
// 156.716 us; speedup vs baseline: 1.1885x; 1.0238x over previous
//
#include <hip/hip_runtime.h>

#define NN 2048
#define HALF 1024
#define CC 128
#define EE 65536
#define CAP 128

typedef unsigned short u16;

__device__ __forceinline__ float sigm(float v){ return 1.0f/(1.0f + __expf(-v)); }

__device__ __forceinline__ float dinv_lo(int i, const int* __restrict__ cnt,
                                         const float* __restrict__ colsum){
  return rsqrtf(1.0f + (float)cnt[i] + colsum[i]);
}
__device__ __forceinline__ float dinv_any(int i, const int* __restrict__ cnt,
                                          const float* __restrict__ colsum){
  float cs = (i < HALF) ? colsum[i] : 0.0f;
  return rsqrtf(1.0f + (float)cnt[i] + cs);
}

// ---------------- K1: prep (512 blocks) — H0 matmul runs CONCURRENTLY with sigmoid/bucket
//  all: bias-seed out (first 256 blocks)
//  [0,128):   SpRaw = sigmoid(my), colsum atomics
//  [128,256): bucket sparse edges by dst (512 edges/block)
//  [256,512): H0 = x @ W1 (8 rows/block)
__global__ __launch_bounds__(256) void k_prep(
    const float* __restrict__ my, const int* __restrict__ ei, const float* __restrict__ x,
    const float* __restrict__ W1,
    const float* __restrict__ bmu, const float* __restrict__ bls,
    float* __restrict__ SpRaw, float* __restrict__ colsum,
    int* __restrict__ cnt, u16* __restrict__ bucket, float* __restrict__ H0,
    float* __restrict__ out)
{
  __shared__ float la[8][CC];
  int b = blockIdx.x, t = threadIdx.x;
  int gid = b*256 + t;                    // 0..131071
  if (gid < 65536) {                      // 65536 float4 = full out
    int g4 = (gid & 15)*4;
    const float* bb = (gid < 32768) ? bmu : bls;
    ((float4*)out)[gid] = make_float4(bb[g4], bb[g4+1], bb[g4+2], bb[g4+3]);
  }

  if (b < 128) {
    int c0 = t*4;
    float cs0=0.f, cs1=0.f, cs2=0.f, cs3=0.f;
    #pragma unroll 2
    for (int rr=0; rr<8; ++rr){
      int r = b*8 + rr;
      float4 v = *(const float4*)(my + (size_t)r*NN + c0);
      float s0=sigm(v.x), s1=sigm(v.y), s2=sigm(v.z), s3=sigm(v.w);
      *(float4*)(SpRaw + (size_t)r*HALF + c0) = make_float4(s0,s1,s2,s3);
      cs0+=s0; cs1+=s1; cs2+=s2; cs3+=s3;
    }
    atomicAdd(&colsum[c0+0], cs0);
    atomicAdd(&colsum[c0+1], cs1);
    atomicAdd(&colsum[c0+2], cs2);
    atomicAdd(&colsum[c0+3], cs3);
  } else if (b < 256) {
    int e0 = (b-128)*512 + t;
    #pragma unroll
    for (int i=0;i<2;i++){
      int e = e0 + i*256;
      int s = ei[e], d = ei[EE + e];
      int slot = atomicAdd(&cnt[d], 1);
      if (slot < CAP) bucket[d*CAP + slot] = (u16)s;
    }
  } else {
    int row0 = (b-256)*8;
    #pragma unroll
    for (int i=0;i<4;i++){
      int idx = i*256 + t;
      la[idx>>7][idx&127] = x[(size_t)row0*CC + idx];
    }
    __syncthreads();
    int f = t & 127, rh = t >> 7;
    const float4* a0 = (const float4*)la[rh*4+0];
    const float4* a1 = (const float4*)la[rh*4+1];
    const float4* a2 = (const float4*)la[rh*4+2];
    const float4* a3 = (const float4*)la[rh*4+3];
    float o0=0.f, o1=0.f, o2=0.f, o3=0.f;
    #pragma unroll 4
    for (int k4=0;k4<32;k4++){
      float4 v0=a0[k4], v1=a1[k4], v2=a2[k4], v3=a3[k4];
      float w0 = W1[(k4*4+0)*CC + f];
      float w1 = W1[(k4*4+1)*CC + f];
      float w2 = W1[(k4*4+2)*CC + f];
      float w3 = W1[(k4*4+3)*CC + f];
      o0=fmaf(v0.x,w0,o0); o0=fmaf(v0.y,w1,o0); o0=fmaf(v0.z,w2,o0); o0=fmaf(v0.w,w3,o0);
      o1=fmaf(v1.x,w0,o1); o1=fmaf(v1.y,w1,o1); o1=fmaf(v1.z,w2,o1); o1=fmaf(v1.w,w3,o1);
      o2=fmaf(v2.x,w0,o2); o2=fmaf(v2.y,w1,o2); o2=fmaf(v2.z,w2,o2); o2=fmaf(v2.w,w3,o2);
      o3=fmaf(v3.x,w0,o3); o3=fmaf(v3.y,w1,o3); o3=fmaf(v3.z,w2,o3); o3=fmaf(v3.w,w3,o3);
    }
    H0[(size_t)(row0 + rh*4 + 0)*CC + f] = o0;
    H0[(size_t)(row0 + rh*4 + 1)*CC + f] = o1;
    H0[(size_t)(row0 + rh*4 + 2)*CC + f] = o2;
    H0[(size_t)(row0 + rh*4 + 3)*CC + f] = o3;
  }
}

// ---------------- K2: layer1 partials (768 blocks, NO atomics)
//  dense [0,512): 16 d/block, float2/lane, 8 r-chunks of 128, 4-row load batching
//  sparse [512,768): 8 dst/block, half-wave float4 -> SP
__global__ __launch_bounds__(256) void k_agg1(
  const float* __restrict__ SpRaw, const float* __restrict__ H0,
  const int* __restrict__ cnt, const float* __restrict__ colsum,
  const u16* __restrict__ bucket,
  float* __restrict__ SP, float* __restrict__ DP)
{
  int b = blockIdx.x, t = threadIdx.x;
  if (b < 512) {
    __shared__ float srow[128];
    int chunk = b & 7, r0 = chunk*128;
    if (t < 128) srow[t] = dinv_lo(r0 + t, cnt, colsum);
    __syncthreads();
    int lane = t & 63, f0 = lane*2;
    int dbase = (b>>3)*16 + (t>>6)*4;
    float a00=0.f,a01=0.f,a10=0.f,a11=0.f,a20=0.f,a21=0.f,a30=0.f,a31=0.f;
    #pragma unroll 2
    for (int rr=0; rr<128; rr+=4){
      int r = r0 + rr;
      float2 v0 = *(const float2*)(H0 + (size_t)(r+0)*CC + f0);
      float2 v1 = *(const float2*)(H0 + (size_t)(r+1)*CC + f0);
      float2 v2 = *(const float2*)(H0 + (size_t)(r+2)*CC + f0);
      float2 v3 = *(const float2*)(H0 + (size_t)(r+3)*CC + f0);
      float4 s0 = *(const float4*)(SpRaw + (size_t)(r+0)*HALF + dbase);
      float4 s1 = *(const float4*)(SpRaw + (size_t)(r+1)*HALF + dbase);
      float4 s2 = *(const float4*)(SpRaw + (size_t)(r+2)*HALF + dbase);
      float4 s3 = *(const float4*)(SpRaw + (size_t)(r+3)*HALF + dbase);
      float c0 = srow[rr+0], c1 = srow[rr+1], c2 = srow[rr+2], c3 = srow[rr+3];
      float fx, fy;
      fx = v0.x*c0; fy = v0.y*c0;
      a00=fmaf(s0.x,fx,a00); a01=fmaf(s0.x,fy,a01);
      a10=fmaf(s0.y,fx,a10); a11=fmaf(s0.y,fy,a11);
      a20=fmaf(s0.z,fx,a20); a21=fmaf(s0.z,fy,a21);
      a30=fmaf(s0.w,fx,a30); a31=fmaf(s0.w,fy,a31);
      fx = v1.x*c1; fy = v1.y*c1;
      a00=fmaf(s1.x,fx,a00); a01=fmaf(s1.x,fy,a01);
      a10=fmaf(s1.y,fx,a10); a11=fmaf(s1.y,fy,a11);
      a20=fmaf(s1.z,fx,a20); a21=fmaf(s1.z,fy,a21);
      a30=fmaf(s1.w,fx,a30); a31=fmaf(s1.w,fy,a31);
      fx = v2.x*c2; fy = v2.y*c2;
      a00=fmaf(s2.x,fx,a00); a01=fmaf(s2.x,fy,a01);
      a10=fmaf(s2.y,fx,a10); a11=fmaf(s2.y,fy,a11);
      a20=fmaf(s2.z,fx,a20); a21=fmaf(s2.z,fy,a21);
      a30=fmaf(s2.w,fx,a30); a31=fmaf(s2.w,fy,a31);
      fx = v3.x*c3; fy = v3.y*c3;
      a00=fmaf(s3.x,fx,a00); a01=fmaf(s3.x,fy,a01);
      a10=fmaf(s3.y,fx,a10); a11=fmaf(s3.y,fy,a11);
      a20=fmaf(s3.z,fx,a20); a21=fmaf(s3.z,fy,a21);
      a30=fmaf(s3.w,fx,a30); a31=fmaf(s3.w,fy,a31);
    }
    float d0=dinv_lo(dbase+0,cnt,colsum), d1=dinv_lo(dbase+1,cnt,colsum);
    float d2=dinv_lo(dbase+2,cnt,colsum), d3=dinv_lo(dbase+3,cnt,colsum);
    float* o = DP + ((size_t)chunk*HALF + dbase)*CC + f0;
    o[0*CC+0]=a00*d0; o[0*CC+1]=a01*d0;
    o[1*CC+0]=a10*d1; o[1*CC+1]=a11*d1;
    o[2*CC+0]=a20*d2; o[2*CC+1]=a21*d2;
    o[3*CC+0]=a30*d3; o[3*CC+1]=a31*d3;
  } else {
    __shared__ float sdinv[NN];
    #pragma unroll
    for (int i=0;i<8;i++){
      int j = i*256 + t;
      float cs = (j < HALF) ? colsum[j] : 0.0f;
      sdinv[j] = rsqrtf(1.0f + (float)cnt[j] + cs);
    }
    __syncthreads();
    int w = t>>6, hw = (t>>5)&1, l = t&31;
    int d = (b-512)*8 + w*2 + hw;
    int f0 = l*4;
    float dd = sdinv[d];
    float4 sv = *(const float4*)(H0 + (size_t)d*CC + f0);
    float ax=dd*sv.x, ay=dd*sv.y, az=dd*sv.z, aw=dd*sv.w;   // self-loop
    int m = cnt[d]; m = m > CAP ? CAP : m;
    const u16* bk = bucket + d*CAP;
    int j = 0;
    for (; j+1 < m; j += 2){
      unsigned pr = *(const unsigned*)(bk + j);
      int s0 = pr & 0xffff, s1 = pr >> 16;
      float w0 = sdinv[s0], w1 = sdinv[s1];
      float4 v0 = *(const float4*)(H0 + (size_t)s0*CC + f0);
      float4 v1 = *(const float4*)(H0 + (size_t)s1*CC + f0);
      ax=fmaf(w0,v0.x,ax); ay=fmaf(w0,v0.y,ay); az=fmaf(w0,v0.z,az); aw=fmaf(w0,v0.w,aw);
      ax=fmaf(w1,v1.x,ax); ay=fmaf(w1,v1.y,ay); az=fmaf(w1,v1.z,az); aw=fmaf(w1,v1.w,aw);
    }
    if (j < m){
      int s0 = bk[j];
      float w0 = sdinv[s0];
      float4 v0 = *(const float4*)(H0 + (size_t)s0*CC + f0);
      ax=fmaf(w0,v0.x,ax); ay=fmaf(w0,v0.y,ay); az=fmaf(w0,v0.z,az); aw=fmaf(w0,v0.w,aw);
    }
    *(float4*)(SP + (size_t)d*CC + f0) = make_float4(dd*ax, dd*ay, dd*az, dd*aw);
  }
}

// ---------------- K3: mid (512 blocks, 4 rows each), SINGLE matmul:
//  Gm = ( relu(SP + sum_8 DP + b1) @ [Wmu|Wls] ) * dinv[row]
__global__ __launch_bounds__(256) void k_mid(
  const float* __restrict__ SP, const float* __restrict__ DP,
  const float* __restrict__ b1,
  const float* __restrict__ Wmu, const float* __restrict__ Wls,
  const int* __restrict__ cnt, const float* __restrict__ colsum,
  float* __restrict__ Gm)
{
  __shared__ float la[4][CC];
  int b = blockIdx.x, t = threadIdx.x;
  int row0 = b*4;
  #pragma unroll
  for (int i=0;i<2;i++){
    int idx = i*256 + t;                  // 0..511 covers 4 rows x 128
    int r = row0 + (idx>>7), c = idx & 127;
    float v = SP[(size_t)r*CC + c];
    if (r < HALF){
      #pragma unroll
      for (int k=0;k<8;k++) v += DP[((size_t)k*HALF + r)*CC + c];
    }
    v += b1[c];
    la[idx>>7][c] = v > 0.f ? v : 0.f;
  }
  __syncthreads();
  int f = t & 127, rh = t >> 7, g = f & 63;
  const float* W = (f < 64) ? Wmu : Wls;
  const float4* a0 = (const float4*)la[rh*2+0];
  const float4* a1 = (const float4*)la[rh*2+1];
  float o0=0.f, o1=0.f;
  #pragma unroll 4
  for (int k4=0;k4<32;k4++){
    float4 v0=a0[k4], v1=a1[k4];
    float w0 = W[(k4*4+0)*64 + g];
    float w1 = W[(k4*4+1)*64 + g];
    float w2 = W[(k4*4+2)*64 + g];
    float w3 = W[(k4*4+3)*64 + g];
    o0=fmaf(v0.x,w0,o0); o0=fmaf(v0.y,w1,o0); o0=fmaf(v0.z,w2,o0); o0=fmaf(v0.w,w3,o0);
    o1=fmaf(v1.x,w0,o1); o1=fmaf(v1.y,w1,o1); o1=fmaf(v1.z,w2,o1); o1=fmaf(v1.w,w3,o1);
  }
  int rA = row0 + rh*2;
  Gm[(size_t)(rA+0)*CC + f] = o0 * dinv_any(rA+0, cnt, colsum);
  Gm[(size_t)(rA+1)*CC + f] = o1 * dinv_any(rA+1, cnt, colsum);
}

// ---------------- K4: out += Â-apply(Gm)  (768 blocks, atomics into bias-seeded out)
//  dense [0,512): 16 d/block, float2/lane, 8 r-chunks of 128, 4-row load batching
//  sparse [512,768): 8 dst/block, half-wave float4
__global__ __launch_bounds__(256) void k_agg2(
  const float* __restrict__ SpRaw, const float* __restrict__ Gm,
  const int* __restrict__ cnt, const float* __restrict__ colsum,
  const u16* __restrict__ bucket, float* __restrict__ out)
{
  int b = blockIdx.x, t = threadIdx.x;
  if (b < 512) {
    int lane = t & 63, f0 = lane*2;
    size_t obase = (f0 < 64) ? 0 : (size_t)NN*64;
    int g0 = f0 & 63;
    int dbase = (b>>3)*16 + (t>>6)*4;
    int r0 = (b&7)*128;
    float a00=0.f,a01=0.f,a10=0.f,a11=0.f,a20=0.f,a21=0.f,a30=0.f,a31=0.f;
    #pragma unroll 2
    for (int rr=0; rr<128; rr+=4){
      int r = r0 + rr;
      float2 v0 = *(const float2*)(Gm + (size_t)(r+0)*CC + f0);   // pre-scaled by dinv[r]
      float2 v1 = *(const float2*)(Gm + (size_t)(r+1)*CC + f0);
      float2 v2 = *(const float2*)(Gm + (size_t)(r+2)*CC + f0);
      float2 v3 = *(const float2*)(Gm + (size_t)(r+3)*CC + f0);
      float4 s0 = *(const float4*)(SpRaw + (size_t)(r+0)*HALF + dbase);
      float4 s1 = *(const float4*)(SpRaw + (size_t)(r+1)*HALF + dbase);
      float4 s2 = *(const float4*)(SpRaw + (size_t)(r+2)*HALF + dbase);
      float4 s3 = *(const float4*)(SpRaw + (size_t)(r+3)*HALF + dbase);
      a00=fmaf(s0.x,v0.x,a00); a01=fmaf(s0.x,v0.y,a01);
      a10=fmaf(s0.y,v0.x,a10); a11=fmaf(s0.y,v0.y,a11);
      a20=fmaf(s0.z,v0.x,a20); a21=fmaf(s0.z,v0.y,a21);
      a30=fmaf(s0.w,v0.x,a30); a31=fmaf(s0.w,v0.y,a31);
      a00=fmaf(s1.x,v1.x,a00); a01=fmaf(s1.x,v1.y,a01);
      a10=fmaf(s1.y,v1.x,a10); a11=fmaf(s1.y,v1.y,a11);
      a20=fmaf(s1.z,v1.x,a20); a21=fmaf(s1.z,v1.y,a21);
      a30=fmaf(s1.w,v1.x,a30); a31=fmaf(s1.w,v1.y,a31);
      a00=fmaf(s2.x,v2.x,a00); a01=fmaf(s2.x,v2.y,a01);
      a10=fmaf(s2.y,v2.x,a10); a11=fmaf(s2.y,v2.y,a11);
      a20=fmaf(s2.z,v2.x,a20); a21=fmaf(s2.z,v2.y,a21);
      a30=fmaf(s2.w,v2.x,a30); a31=fmaf(s2.w,v2.y,a31);
      a00=fmaf(s3.x,v3.x,a00); a01=fmaf(s3.x,v3.y,a01);
      a10=fmaf(s3.y,v3.x,a10); a11=fmaf(s3.y,v3.y,a11);
      a20=fmaf(s3.z,v3.x,a20); a21=fmaf(s3.z,v3.y,a21);
      a30=fmaf(s3.w,v3.x,a30); a31=fmaf(s3.w,v3.y,a31);
    }
    float d0=dinv_lo(dbase+0,cnt,colsum), d1=dinv_lo(dbase+1,cnt,colsum);
    float d2=dinv_lo(dbase+2,cnt,colsum), d3=dinv_lo(dbase+3,cnt,colsum);
    float* o = out + obase + (size_t)dbase*64 + g0;
    atomicAdd(o + 0*64 + 0, a00*d0); atomicAdd(o + 0*64 + 1, a01*d0);
    atomicAdd(o + 1*64 + 0, a10*d1); atomicAdd(o + 1*64 + 1, a11*d1);
    atomicAdd(o + 2*64 + 0, a20*d2); atomicAdd(o + 2*64 + 1, a21*d2);
    atomicAdd(o + 3*64 + 0, a30*d3); atomicAdd(o + 3*64 + 1, a31*d3);
  } else {
    int w = t>>6, hw = (t>>5)&1, l = t&31;
    int d = (b-512)*8 + w*2 + hw;
    int f0 = l*4;
    size_t obase = (f0 < 64) ? 0 : (size_t)NN*64;
    int g0 = f0 & 63;
    float4 a = *(const float4*)(Gm + (size_t)d*CC + f0);      // self (pre-scaled)
    float ax=a.x, ay=a.y, az=a.z, aw=a.w;
    int m = cnt[d]; m = m > CAP ? CAP : m;
    const u16* bk = bucket + d*CAP;
    int j = 0;
    for (; j+1 < m; j += 2){
      unsigned pr = *(const unsigned*)(bk + j);
      int s0 = pr & 0xffff, s1 = pr >> 16;
      float4 v0 = *(const float4*)(Gm + (size_t)s0*CC + f0);
      float4 v1 = *(const float4*)(Gm + (size_t)s1*CC + f0);
      ax += v0.x + v1.x; ay += v0.y + v1.y;
      az += v0.z + v1.z; aw += v0.w + v1.w;
    }
    if (j < m){
      int s0 = bk[j];
      float4 v0 = *(const float4*)(Gm + (size_t)s0*CC + f0);
      ax += v0.x; ay += v0.y; az += v0.z; aw += v0.w;
    }
    float dd = dinv_any(d, cnt, colsum);
    float* o = out + obase + (size_t)d*64 + g0;
    atomicAdd(o + 0, dd*ax); atomicAdd(o + 1, dd*ay);
    atomicAdd(o + 2, dd*az); atomicAdd(o + 3, dd*aw);
  }
}

extern "C" void kernel_launch(void* const* d_in, const int* in_sizes, int n_in,
                              void* d_out, int out_size, void* d_ws, size_t ws_size,
                              hipStream_t stream)
{
  (void)in_sizes; (void)n_in; (void)out_size; (void)ws_size;
  const float* x   = (const float*)d_in[0];
  const float* my  = (const float*)d_in[1];
  const float* W1  = (const float*)d_in[2];
  const float* b1  = (const float*)d_in[3];
  const float* Wmu = (const float*)d_in[4];
  const float* bmu = (const float*)d_in[5];
  const float* Wls = (const float*)d_in[6];
  const float* bls = (const float*)d_in[7];
  const int*   ei  = (const int*)d_in[8];
  float* out = (float*)d_out;
  char* ws = (char*)d_ws;

  // ws layout — memset covers [0, 12288): cnt, colsum
  int*   cnt    = (int*)  (ws + 0);        //    8192 B (memset 0)
  float* colsum = (float*)(ws + 8192);     //    4096 B (memset 0)
  u16*   bucket = (u16*)  (ws + 12288);    //  524288 B
  float* SpRaw  = (float*)(ws + 536576);   // 4194304 B
  float* H0     = (float*)(ws + 4730880);  // 1048576 B
  float* Gm     = (float*)(ws + 5779456);  // 1048576 B
  float* SP     = (float*)(ws + 6828032);  // 1048576 B
  float* DP     = (float*)(ws + 7876608);  // 4194304 B  (8*1024*128*4)

  hipMemsetAsync(ws, 0, 12288, stream);
  k_prep<<<512, 256, 0, stream>>>(my, ei, x, W1, bmu, bls,
                                  SpRaw, colsum, cnt, bucket, H0, out);
  k_agg1<<<768, 256, 0, stream>>>(SpRaw, H0, cnt, colsum, bucket, SP, DP);
  k_mid <<<512, 256, 0, stream>>>(SP, DP, b1, Wmu, Wls, cnt, colsum, Gm);
  k_agg2<<<768, 256, 0, stream>>>(SpRaw, Gm, cnt, colsum, bucket, out);
}